// Round 1
// baseline (3327.094 us; speedup 1.0000x reference)
//
#include <hip/hip_runtime.h>
#include <math.h>

#define HD 128

// ---------------------------------------------------------------- zero fill
__global__ void __launch_bounds__(256) zero_kernel(float4* __restrict__ p, long n4) {
  long i = (long)blockIdx.x * blockDim.x + threadIdx.x;
  long stride = (long)gridDim.x * blockDim.x;
  float4 z = make_float4(0.f, 0.f, 0.f, 0.f);
  for (; i < n4; i += stride) p[i] = z;
}

// ------------------------------------------------- sigmoid(x[:2] @ W^T + b)
// rows = flattened (s,node) for s in {0,1}: x row r lives at x + r*HD,
// output SI row r at SI + r*HD (S = rows [0,N), I = rows [N,2N)).
// W kept in natural layout in LDS; lane-rotation hh=(step+o)&127 makes both
// the W read (bank = (step+o)%32, 2-way) and the x read conflict-free.
__global__ void __launch_bounds__(256) sigmoid_gemm(const float* __restrict__ x,
                                                    const float* __restrict__ W,
                                                    const float* __restrict__ b,
                                                    float* __restrict__ SI,
                                                    int nrows) {
  __shared__ float Wl[HD * HD];     // 64 KB
  __shared__ float xs[16 * HD];     // 8 KB
  for (int i = threadIdx.x; i < HD * HD; i += 256) Wl[i] = W[i];
  int row0 = blockIdx.x * 16;
  for (int i = threadIdx.x; i < 16 * HD; i += 256) {
    int r = row0 + (i >> 7);
    xs[i] = (r < nrows) ? x[(long)row0 * HD + i] : 0.f;
  }
  __syncthreads();

  int o = threadIdx.x & (HD - 1);   // output channel 0..127
  int half = threadIdx.x >> 7;      // 0/1 -> rows half*8 .. half*8+7
  float acc[8];
#pragma unroll
  for (int r = 0; r < 8; ++r) acc[r] = 0.f;

#pragma unroll 4
  for (int step = 0; step < HD; ++step) {
    int hh = (step + o) & (HD - 1);
    float wv = Wl[o * HD + hh];
#pragma unroll
    for (int r = 0; r < 8; ++r)
      acc[r] = fmaf(xs[(half * 8 + r) * HD + hh], wv, acc[r]);
  }

  float bb = b[o];
#pragma unroll
  for (int r = 0; r < 8; ++r) {
    int row = row0 + half * 8 + r;
    if (row < nrows) {
      float v = acc[r] + bb;
      SI[(long)row * HD + o] = 1.f / (1.f + __expf(-v));
    }
  }
}

// ------------------------------------------------------------ edge scatter
// AI[rows[e]] += I[cols[e]]  (128 floats per edge). Half-wave (32 lanes) per
// edge, float4 per lane; atomics are device-scope global_atomic_add_f32.
__global__ void __launch_bounds__(256) edge_scatter(const float* __restrict__ I,
                                                    const int* __restrict__ rows,
                                                    const int* __restrict__ cols,
                                                    float* __restrict__ AI,
                                                    int n_edges) {
  long tid = (long)blockIdx.x * 256 + threadIdx.x;
  int e = (int)(tid >> 5);
  if (e >= n_edges) return;
  int lane = (int)(tid & 31);
  int col = cols[e];
  int row = rows[e];
  float4 v = ((const float4*)(I + (long)col * HD))[lane];
  float* dst = AI + (long)row * HD + lane * 4;
  atomicAdd(dst + 0, v.x);
  atomicAdd(dst + 1, v.y);
  atomicAdd(dst + 2, v.z);
  atomicAdd(dst + 3, v.w);
}

// --------------------------------------------------------------- epilogue
// out0 currently holds AI; overwrite with dS, write dI, dR. out3 already 0.
__global__ void __launch_bounds__(256) finalize(const float* __restrict__ S,
                                                const float* __restrict__ I,
                                                const float* __restrict__ x3,
                                                float* __restrict__ out,
                                                int n_nodes) {
  long i4 = (long)blockIdx.x * 256 + threadIdx.x;
  long total4 = (long)n_nodes * (HD / 4);
  if (i4 >= total4) return;
  int n = (int)(i4 >> 5);  // node = (i4*4)/128
  float beta = x3[(long)n * HD + 0];
  float gamma = x3[(long)n * HD + 1];

  float4* o0 = (float4*)out;
  float4 ai = o0[i4];
  float4 s = ((const float4*)S)[i4];
  float4 ii = ((const float4*)I)[i4];

  float4 dS, dI, dR;
  dS.x = -beta * ai.x * s.x;
  dS.y = -beta * ai.y * s.y;
  dS.z = -beta * ai.z * s.z;
  dS.w = -beta * ai.w * s.w;
  dI.x = -dS.x - gamma * ii.x;
  dI.y = -dS.y - gamma * ii.y;
  dI.z = -dS.z - gamma * ii.z;
  dI.w = -dS.w - gamma * ii.w;
  dR.x = gamma * ii.x;
  dR.y = gamma * ii.y;
  dR.z = gamma * ii.z;
  dR.w = gamma * ii.w;

  o0[i4] = dS;
  o0[total4 + i4] = dI;
  o0[2 * total4 + i4] = dR;
}

// ---------------------------------------------------------------- launcher
extern "C" void kernel_launch(void* const* d_in, const int* in_sizes, int n_in,
                              void* d_out, int out_size, void* d_ws, size_t ws_size,
                              hipStream_t stream) {
  const float* x = (const float*)d_in[0];
  const float* W = (const float*)d_in[1];
  const float* b = (const float*)d_in[2];
  const int* rows = (const int*)d_in[3];
  const int* cols = (const int*)d_in[4];
  float* out = (float*)d_out;

  int n_nodes = in_sizes[0] / (4 * HD);
  int n_edges = in_sizes[3];
  int nrows = 2 * n_nodes;

  float* S = (float*)d_ws;                 // n_nodes*HD floats
  float* I = S + (long)n_nodes * HD;       // n_nodes*HD floats

  long n4 = (long)n_nodes * HD / 4;        // float4 count of one (N,128) plane
  int zb = (int)((n4 + 255) / 256);

  // zero AI accumulator (out plane 0) and out plane 3
  zero_kernel<<<zb, 256, 0, stream>>>((float4*)out, n4);
  zero_kernel<<<zb, 256, 0, stream>>>((float4*)(out + 3 * (long)n_nodes * HD), n4);

  // S, I = sigmoid(x[:2] @ W^T + b)
  int gblocks = (nrows + 15) / 16;
  sigmoid_gemm<<<gblocks, 256, 0, stream>>>(x, W, b, S, nrows);

  // AI += I[cols] scattered to rows (into out plane 0)
  long escatter_threads = (long)n_edges * 32;
  int eblocks = (int)((escatter_threads + 255) / 256);
  edge_scatter<<<eblocks, 256, 0, stream>>>(I, rows, cols, out, n_edges);

  // epilogue
  finalize<<<zb, 256, 0, stream>>>(S, I, x + 3 * (long)n_nodes * HD, out, n_nodes);
}